// Round 4
// baseline (2701.413 us; speedup 1.0000x reference)
//
#include <hip/hip_runtime.h>
#include <cstdint>

typedef unsigned short u16;
typedef unsigned int u32;
typedef __bf16 bf16_t;
typedef bf16_t bf16x8 __attribute__((ext_vector_type(8)));
typedef float f32x4 __attribute__((ext_vector_type(4)));

#define DMODEL 4096
#define DFF 11008
#define MROWS 8192

__device__ __forceinline__ u16 f2bf(float f) {
  u32 u = __builtin_bit_cast(u32, f);
  u += 0x7FFFu + ((u >> 16) & 1u);   // RNE
  return (u16)(u >> 16);
}
__device__ __forceinline__ float bf2f(u16 h) {
  return __builtin_bit_cast(float, (u32)h << 16);
}

// async global->LDS, 16B per lane, wave-uniform LDS base + lane*16
#define GLD16(gptr, lptr)                                                  \
  __builtin_amdgcn_global_load_lds(                                        \
      (const __attribute__((address_space(1))) u32*)(gptr),                \
      (__attribute__((address_space(3))) u32*)(lptr), 16, 0, 0)

// ---------------- x -> bf16 ----------------
__global__ void k_cvt_x(const float* __restrict__ x, u16* __restrict__ xb) {
  size_t i = (size_t)blockIdx.x * blockDim.x + threadIdx.x;
  float4 v = reinterpret_cast<const float4*>(x)[i];
  ushort4 o;
  o.x = f2bf(v.x); o.y = f2bf(v.y); o.z = f2bf(v.z); o.w = f2bf(v.w);
  reinterpret_cast<ushort4*>(xb)[i] = o;
}

// ------- dequant (q - z) * s, write TRANSPOSED wT[N][K] as bf16 -------
__global__ void k_dequant_T(const int* __restrict__ q, const int* __restrict__ z,
                            const float* __restrict__ s, u16* __restrict__ wT,
                            int K, int N) {
  __shared__ u16 tile[32][33];
  const int tx = threadIdx.x & 31, ty = threadIdx.x >> 5;
  const int n0 = blockIdx.x << 5, k0 = blockIdx.y << 5;
#pragma unroll
  for (int i = 0; i < 4; ++i) {
    int r = ty + i * 8;
    int k = k0 + r;
    int g = k >> 7;
    size_t zoff = (size_t)g * N + n0 + tx;
    float val = (float)(q[(size_t)k * N + n0 + tx] - z[zoff]) * s[zoff];
    tile[r][tx] = f2bf(val);
  }
  __syncthreads();
#pragma unroll
  for (int i = 0; i < 4; ++i) {
    int r = ty + i * 8;
    wT[(size_t)(n0 + r) * K + k0 + tx] = tile[tx][r];
  }
}

// ======== 256x256 4-phase GEMM: C[M,N] = A[M,K] * BT[N,K]^T ========
// 512 thr = 8 waves (2M x 4N, 128x64 out each), BK=64 in 2 K-halves,
// dbuf LDS 128KB. Phase = (buf, khalf): 12 ds_read_b128 + 32 MFMA,
// 2 barriers. mh1 A-frag reads issued BETWEEN the two 16-MFMA clusters
// (compiler interleaves -> LDS/MFMA overlap). Stage 2 chunks (4 GLD16)
// per phase; every region re-staged 1 barrier after its last read;
// vmcnt(4) checkpoints at phases 2,4 give each chunk >=2 phases of
// flight (~4000cyc >> 900cyc HBM latency). Raw s_barrier (no drain).
// Swizzle: LDS[row][s] = G[row][s^((row>>1)&3)], verified 0-conflict.
template <int EPI>
__global__ __launch_bounds__(512, 2) void k_gemm4(
    const u16* __restrict__ A, const u16* __restrict__ BT,
    void* C, int Mdim, int Ndim, int Kdim) {
  __shared__ u16 As[2][2][256 * 32];  // [buf][khalf][row*32+col]
  __shared__ u16 Bs[2][2][256 * 32];

  const int nbn = Ndim >> 8;
  int bid = blockIdx.x;
  { const int cpx = gridDim.x >> 3; bid = (bid & 7) * cpx + (bid >> 3); }
  const int m0 = (bid / nbn) << 8;
  const int n0 = (bid % nbn) << 8;
  const int t = threadIdx.x;
  const int lane = t & 63;
  const int wid = t >> 6;
  const int wr = wid >> 2, wc = wid & 3;
  const int r16 = lane & 15, quad = lane >> 4;

  // staging: lane l -> lds row wid*16 + l/4, slot l&3; source slot
  // pre-swizzled (l&3)^((l>>3)&3) = slot ^ ((row>>1)&3)
  const int lrow4 = lane >> 2;
  const int sslot = ((lane & 3) ^ ((lane >> 3) & 3)) << 3;  // u16 units
  const u16* Asrc = A + (size_t)(m0 + wid * 16 + lrow4) * Kdim + sslot;
  const u16* Bsrc = BT + (size_t)(n0 + wid * 16 + lrow4) * Kdim + sslot;
  const size_t rstep = (size_t)128 * Kdim;
  const int lb = wid * 512;
  const int ntiles = Kdim >> 6;

#define SA(tt, kh, bf) do {                                                \
    int ttw = (tt) < ntiles ? (tt) : (tt) - ntiles;                        \
    size_t ko = ((size_t)ttw << 6) + ((kh) << 5);                          \
    GLD16(Asrc + ko,         &As[bf][kh][lb]);                             \
    GLD16(Asrc + ko + rstep, &As[bf][kh][lb + 4096]);                      \
  } while (0)
#define SB(tt, kh, bf) do {                                                \
    int ttw = (tt) < ntiles ? (tt) : (tt) - ntiles;                        \
    size_t ko = ((size_t)ttw << 6) + ((kh) << 5);                          \
    GLD16(Bsrc + ko,         &Bs[bf][kh][lb]);                             \
    GLD16(Bsrc + ko + rstep, &Bs[bf][kh][lb + 4096]);                      \
  } while (0)

  // fragment read offsets (swizzled): slot = quad ^ ((r16>>1)&3)
  const int fragoff = (quad ^ ((r16 >> 1) & 3)) << 3;
  const int abase = (wr * 128 + r16) * 32 + fragoff;
  const int bbase = (wc * 64 + r16) * 32 + fragoff;

  f32x4 acc[8][4];
  const f32x4 zf = {0.f, 0.f, 0.f, 0.f};
#pragma unroll
  for (int mf = 0; mf < 8; ++mf)
#pragma unroll
    for (int nf = 0; nf < 4; ++nf) acc[mf][nf] = zf;

#define BAR asm volatile("s_barrier" ::: "memory")
#define VM4 asm volatile("s_waitcnt vmcnt(4)" ::: "memory")

  // Phase = (buf, kk): 32 MFMA (both M-halves), 12 ds_read, 2 barriers.
#define PH(bf, kk, STG, VMW) do {                                          \
    bf16x8 av[4], bv[4], av2[4];                                           \
    _Pragma("unroll") for (int ii = 0; ii < 4; ++ii)                       \
      av[ii] = *reinterpret_cast<const bf16x8*>(                           \
          &As[bf][kk][abase + ii * 512]);                                  \
    _Pragma("unroll") for (int nn = 0; nn < 4; ++nn)                       \
      bv[nn] = *reinterpret_cast<const bf16x8*>(                           \
          &Bs[bf][kk][bbase + nn * 512]);                                  \
    STG;                                                                   \
    BAR;                                                                   \
    __builtin_amdgcn_s_setprio(1);                                         \
    _Pragma("unroll") for (int ii = 0; ii < 4; ++ii)                       \
      _Pragma("unroll") for (int nn = 0; nn < 4; ++nn)                     \
        acc[ii][nn] = __builtin_amdgcn_mfma_f32_16x16x32_bf16(             \
            av[ii], bv[nn], acc[ii][nn], 0, 0, 0);                         \
    _Pragma("unroll") for (int ii = 0; ii < 4; ++ii)                       \
      av2[ii] = *reinterpret_cast<const bf16x8*>(                          \
          &As[bf][kk][abase + 2048 + ii * 512]);                           \
    _Pragma("unroll") for (int ii = 0; ii < 4; ++ii)                       \
      _Pragma("unroll") for (int nn = 0; nn < 4; ++nn)                     \
        acc[4 + ii][nn] = __builtin_amdgcn_mfma_f32_16x16x32_bf16(         \
            av2[ii], bv[nn], acc[4 + ii][nn], 0, 0, 0);                    \
    __builtin_amdgcn_s_setprio(0);                                         \
    VMW;                                                                   \
    BAR;                                                                   \
  } while (0)

  // prologue: tile0 full + tile1-kh0 = 12 GLD; wait all but tile1-kh0.
  SA(0, 0, 0); SB(0, 0, 0); SA(0, 1, 0); SB(0, 1, 0); SA(1, 0, 1); SB(1, 0, 1);
  VM4;
  BAR;

  const int NI = ntiles >> 1;
  for (int it = 0; it < NI; ++it) {
    const int t0 = it * 2;
    PH(0, 0, { SA(t0 + 1, 1, 1); SB(t0 + 1, 1, 1); }, (void)0);  // buf1-kh1
    PH(0, 1, { SA(t0 + 2, 0, 0); SB(t0 + 2, 0, 0); }, VM4);      // buf0-kh0
    PH(1, 0, { SA(t0 + 2, 1, 0); SB(t0 + 2, 1, 0); }, (void)0);  // buf0-kh1
    PH(1, 1, { SA(t0 + 3, 0, 1); SB(t0 + 3, 0, 1); }, VM4);      // buf1-kh0
  }
  asm volatile("s_waitcnt vmcnt(0)" ::: "memory");

  // epilogue. C/D layout: col = lane&15, row = quad*4 + j (m89-verified)
  const int rb0 = m0 + wr * 128 + quad * 4;
  const int cb0 = n0 + wc * 64 + r16;
#pragma unroll
  for (int mf = 0; mf < 8; ++mf) {
#pragma unroll
    for (int nf = 0; nf < 4; ++nf) {
      f32x4 v = acc[mf][nf];
      int row = rb0 + mf * 16;
      int col = cb0 + nf * 16;
#pragma unroll
      for (int j = 0; j < 4; ++j) {
        size_t idx = (size_t)(row + j) * Ndim + col;
        if constexpr (EPI == 0) {
          ((u16*)C)[idx] = f2bf(v[j]);
        } else if constexpr (EPI == 1) {
          u16* Cp = (u16*)C;
          float g = bf2f(Cp[idx]);
          float sv = g / (1.f + __expf(-g));
          Cp[idx] = f2bf(sv * v[j]);
        } else {
          ((float*)C)[idx] = v[j];
        }
      }
    }
  }
#undef SA
#undef SB
#undef PH
#undef BAR
#undef VM4
}

extern "C" void kernel_launch(void* const* d_in, const int* in_sizes, int n_in,
                              void* d_out, int out_size, void* d_ws, size_t ws_size,
                              hipStream_t stream) {
  const float* x  = (const float*)d_in[0];
  const int*   qg = (const int*)d_in[1];
  const int*   zg = (const int*)d_in[2];
  const float* sg = (const float*)d_in[3];
  const int*   qu = (const int*)d_in[4];
  const int*   zu = (const int*)d_in[5];
  const float* su = (const float*)d_in[6];
  const int*   qd = (const int*)d_in[7];
  const int*   zd = (const int*)d_in[8];
  const float* sd = (const float*)d_in[9];
  float* out = (float*)d_out;

  char* ws = (char*)d_ws;
  const size_t szXB = (size_t)MROWS * DMODEL * 2;
  const size_t szW  = (size_t)DMODEL * DFF * 2;
  u16* xb   = (u16*)(ws);
  u16* wgT  = (u16*)(ws + szXB);
  u16* wuT  = (u16*)(ws + szXB + szW);
  u16* wdT  = (u16*)(ws + szXB + 2 * szW);
  u16* gate = (u16*)(ws + szXB + 3 * szW);  // [M][DFF] bf16; becomes h in place

  k_cvt_x<<<(MROWS * DMODEL) / 1024, 256, 0, stream>>>(x, xb);
  k_dequant_T<<<dim3(DFF / 32, DMODEL / 32), 256, 0, stream>>>(qg, zg, sg, wgT, DMODEL, DFF);
  k_dequant_T<<<dim3(DFF / 32, DMODEL / 32), 256, 0, stream>>>(qu, zu, su, wuT, DMODEL, DFF);
  k_dequant_T<<<dim3(DMODEL / 32, DFF / 32), 256, 0, stream>>>(qd, zd, sd, wdT, DFF, DMODEL);

  k_gemm4<0><<<(MROWS / 256) * (DFF / 256), 512, 0, stream>>>(xb, wgT, gate, MROWS, DFF, DMODEL);
  k_gemm4<1><<<(MROWS / 256) * (DFF / 256), 512, 0, stream>>>(xb, wuT, gate, MROWS, DFF, DMODEL);
  k_gemm4<2><<<(MROWS / 256) * (DMODEL / 256), 512, 0, stream>>>(gate, wdT, out, MROWS, DMODEL, DFF);
}

// Round 5
// 2319.586 us; speedup vs baseline: 1.1646x; 1.1646x over previous
//
#include <hip/hip_runtime.h>
#include <cstdint>

typedef unsigned short u16;
typedef unsigned int u32;
typedef __bf16 bf16_t;
typedef bf16_t bf16x8 __attribute__((ext_vector_type(8)));
typedef float f32x4 __attribute__((ext_vector_type(4)));

#define DMODEL 4096
#define DFF 11008
#define MROWS 8192

__device__ __forceinline__ u16 f2bf(float f) {
  u32 u = __builtin_bit_cast(u32, f);
  u += 0x7FFFu + ((u >> 16) & 1u);   // RNE
  return (u16)(u >> 16);
}
__device__ __forceinline__ float bf2f(u16 h) {
  return __builtin_bit_cast(float, (u32)h << 16);
}

// async global->LDS, 16B per lane, wave-uniform LDS base + lane*16
#define GLD16(gptr, lptr)                                                  \
  __builtin_amdgcn_global_load_lds(                                        \
      (const __attribute__((address_space(1))) u32*)(gptr),                \
      (__attribute__((address_space(3))) u32*)(lptr), 16, 0, 0)

// ---------------- x -> bf16 ----------------
__global__ void k_cvt_x(const float* __restrict__ x, u16* __restrict__ xb) {
  size_t i = (size_t)blockIdx.x * blockDim.x + threadIdx.x;
  float4 v = reinterpret_cast<const float4*>(x)[i];
  ushort4 o;
  o.x = f2bf(v.x); o.y = f2bf(v.y); o.z = f2bf(v.z); o.w = f2bf(v.w);
  reinterpret_cast<ushort4*>(xb)[i] = o;
}

// ------- dequant (q - z) * s, write TRANSPOSED wT[N][K] as bf16 -------
// vectorized: int4 q/z loads, float4 s, ushort4 stores. 32k x 32n per block.
__global__ void k_dequant_T(const int* __restrict__ q, const int* __restrict__ z,
                            const float* __restrict__ s, u16* __restrict__ wT,
                            int K, int N) {
  __shared__ u16 tile[32][36];
  const int t = threadIdx.x;
  const int n0 = blockIdx.x << 5, k0 = blockIdx.y << 5;
  {
    const int kr = t >> 3, n4 = (t & 7) << 2;
    const int k = k0 + kr, g = k >> 7;
    const int4 qv = *reinterpret_cast<const int4*>(&q[(size_t)k * N + n0 + n4]);
    const int4 zv = *reinterpret_cast<const int4*>(&z[(size_t)g * N + n0 + n4]);
    const float4 sv = *reinterpret_cast<const float4*>(&s[(size_t)g * N + n0 + n4]);
    ushort4 o;
    o.x = f2bf((float)(qv.x - zv.x) * sv.x);
    o.y = f2bf((float)(qv.y - zv.y) * sv.y);
    o.z = f2bf((float)(qv.z - zv.z) * sv.z);
    o.w = f2bf((float)(qv.w - zv.w) * sv.w);
    *reinterpret_cast<ushort4*>(&tile[kr][n4]) = o;
  }
  __syncthreads();
  {
    const int n = t >> 3, ks = (t & 7) << 2;
    ushort4 o;
    o.x = tile[ks + 0][n];
    o.y = tile[ks + 1][n];
    o.z = tile[ks + 2][n];
    o.w = tile[ks + 3][n];
    *reinterpret_cast<ushort4*>(&wT[(size_t)(n0 + n) * K + k0 + ks]) = o;
  }
}

// locality bid map: XCD owns 4 m-rows; n-outer so 4 consecutive blocks share
// one B panel (L2); A+B working set fits LLC. Requires grid == 32 * nbn.
__device__ __forceinline__ void bid_map(int nbn, int& midx, int& nidx) {
  const int xcd = blockIdx.x & 7, lb = blockIdx.x >> 3;
  midx = xcd * 4 + (lb & 3);
  nidx = lb >> 2;
}

// ======== fused gate+up: h = silu(x@Wg) * (x@Wu), bf16 out ========
// BM=256, BN=128, BK=64 (2 K-halves), 8 waves (2M x 4N, wave-tile 128x32).
// Same 4-phase/vmcnt(4) schedule as the verified R4 kernel: per phase
// 4 GLD16 (A 2 + Bg 1 + Bu 1), 12 ds_read_b128, 32 MFMA, 2 barriers.
// A-fragments feed BOTH Wg and Wu MFMAs (double output per staged byte).
__global__ __launch_bounds__(512, 2) void k_fused(
    const u16* __restrict__ A, const u16* __restrict__ BgT,
    const u16* __restrict__ BuT, u16* __restrict__ H) {
  constexpr int Kdim = DMODEL;
  __shared__ u16 As[2][2][256 * 32];   // 64KB
  __shared__ u16 Bgs[2][2][128 * 32];  // 32KB
  __shared__ u16 Bus[2][2][128 * 32];  // 32KB

  int midx, nidx;
  bid_map(DFF / 128, midx, nidx);
  const int m0 = midx << 8;
  const int n0 = nidx << 7;
  const int t = threadIdx.x;
  const int lane = t & 63;
  const int wid = t >> 6;
  const int wr = wid >> 2, wc = wid & 3;
  const int r16 = lane & 15, quad = lane >> 4;

  // staging: lane l -> lds row base+l/4, slot l&3; source slot pre-swizzled
  const int lrow4 = lane >> 2;
  const int sslot = ((lane & 3) ^ ((lane >> 3) & 3)) << 3;  // u16 units
  const u16* Asrc = A + (size_t)(m0 + wid * 16 + lrow4) * Kdim + sslot;
  const u16* Gsrc = BgT + (size_t)(n0 + wid * 16 + lrow4) * Kdim + sslot;
  const u16* Usrc = BuT + (size_t)(n0 + wid * 16 + lrow4) * Kdim + sslot;
  const size_t rstep = (size_t)128 * Kdim;
  const int lb = wid * 512;
  constexpr int ntiles = Kdim >> 6;  // 64

#define SAF(tt, kh, bf) do {                                               \
    size_t ko = ((size_t)((tt) & (ntiles - 1)) << 6) + ((kh) << 5);        \
    GLD16(Asrc + ko,         &As[bf][kh][lb]);                             \
    GLD16(Asrc + ko + rstep, &As[bf][kh][lb + 4096]);                      \
  } while (0)
#define SGU(tt, kh, bf) do {                                               \
    size_t ko = ((size_t)((tt) & (ntiles - 1)) << 6) + ((kh) << 5);        \
    GLD16(Gsrc + ko, &Bgs[bf][kh][lb]);                                    \
    GLD16(Usrc + ko, &Bus[bf][kh][lb]);                                    \
  } while (0)

  const int fragoff = (quad ^ ((r16 >> 1) & 3)) << 3;
  const int abase = (wr * 128 + r16) * 32 + fragoff;
  const int bbase = (wc * 32 + r16) * 32 + fragoff;

  f32x4 accg[8][2], accu[8][2];
  const f32x4 zf = {0.f, 0.f, 0.f, 0.f};
#pragma unroll
  for (int mf = 0; mf < 8; ++mf)
#pragma unroll
    for (int nf = 0; nf < 2; ++nf) { accg[mf][nf] = zf; accu[mf][nf] = zf; }

#define BAR asm volatile("s_barrier" ::: "memory")
#define VM4 asm volatile("s_waitcnt vmcnt(4)" ::: "memory")

#define PHF(bf, kk, STG, VMW) do {                                         \
    bf16x8 av[4], av2[4], bg[2], bu[2];                                    \
    _Pragma("unroll") for (int ii = 0; ii < 4; ++ii)                       \
      av[ii] = *reinterpret_cast<const bf16x8*>(                           \
          &As[bf][kk][abase + ii * 512]);                                  \
    _Pragma("unroll") for (int nn = 0; nn < 2; ++nn) {                     \
      bg[nn] = *reinterpret_cast<const bf16x8*>(                           \
          &Bgs[bf][kk][bbase + nn * 512]);                                 \
      bu[nn] = *reinterpret_cast<const bf16x8*>(                           \
          &Bus[bf][kk][bbase + nn * 512]);                                 \
    }                                                                      \
    STG;                                                                   \
    BAR;                                                                   \
    __builtin_amdgcn_s_setprio(1);                                         \
    _Pragma("unroll") for (int ii = 0; ii < 4; ++ii)                       \
      _Pragma("unroll") for (int nn = 0; nn < 2; ++nn) {                   \
        accg[ii][nn] = __builtin_amdgcn_mfma_f32_16x16x32_bf16(            \
            av[ii], bg[nn], accg[ii][nn], 0, 0, 0);                        \
        accu[ii][nn] = __builtin_amdgcn_mfma_f32_16x16x32_bf16(            \
            av[ii], bu[nn], accu[ii][nn], 0, 0, 0);                        \
      }                                                                    \
    _Pragma("unroll") for (int ii = 0; ii < 4; ++ii)                       \
      av2[ii] = *reinterpret_cast<const bf16x8*>(                          \
          &As[bf][kk][abase + 2048 + ii * 512]);                           \
    _Pragma("unroll") for (int ii = 0; ii < 4; ++ii)                       \
      _Pragma("unroll") for (int nn = 0; nn < 2; ++nn) {                   \
        accg[4 + ii][nn] = __builtin_amdgcn_mfma_f32_16x16x32_bf16(        \
            av2[ii], bg[nn], accg[4 + ii][nn], 0, 0, 0);                   \
        accu[4 + ii][nn] = __builtin_amdgcn_mfma_f32_16x16x32_bf16(        \
            av2[ii], bu[nn], accu[4 + ii][nn], 0, 0, 0);                   \
      }                                                                    \
    __builtin_amdgcn_s_setprio(0);                                         \
    VMW;                                                                   \
    BAR;                                                                   \
  } while (0)

  // prologue: tile0 full + tile1-kh0 = 12 GLD; wait all but last 4.
  SAF(0, 0, 0); SGU(0, 0, 0); SAF(0, 1, 0); SGU(0, 1, 0);
  SAF(1, 0, 1); SGU(1, 0, 1);
  VM4;
  BAR;

  constexpr int NI = ntiles >> 1;  // 32
  for (int it = 0; it < NI; ++it) {
    const int t0 = it * 2;
    PHF(0, 0, { SAF(t0 + 1, 1, 1); SGU(t0 + 1, 1, 1); }, (void)0);
    PHF(0, 1, { SAF(t0 + 2, 0, 0); SGU(t0 + 2, 0, 0); }, VM4);
    PHF(1, 0, { SAF(t0 + 2, 1, 0); SGU(t0 + 2, 1, 0); }, (void)0);
    PHF(1, 1, { SAF(t0 + 3, 0, 1); SGU(t0 + 3, 0, 1); }, VM4);
  }
  asm volatile("s_waitcnt vmcnt(0)" ::: "memory");

  // epilogue: h = silu(g) * u  (f32 accs -> bf16)
  const int rb0 = m0 + wr * 128 + quad * 4;
  const int cb0 = n0 + wc * 32 + r16;
#pragma unroll
  for (int mf = 0; mf < 8; ++mf) {
#pragma unroll
    for (int nf = 0; nf < 2; ++nf) {
      f32x4 vg = accg[mf][nf];
      f32x4 vu = accu[mf][nf];
      int row = rb0 + mf * 16;
      int col = cb0 + nf * 16;
#pragma unroll
      for (int j = 0; j < 4; ++j) {
        float g = vg[j];
        float sv = g / (1.f + __expf(-g));
        H[(size_t)(row + j) * DFF + col] = f2bf(sv * vu[j]);
      }
    }
  }
#undef SAF
#undef SGU
#undef PHF
#undef BAR
#undef VM4
}

// ======== down GEMM: out[M, DMODEL] = h @ WdT^T, f32 out ========
// R4-verified 256x256 4-phase kernel, EPI=f32, locality bid map.
__global__ __launch_bounds__(512, 2) void k_down(
    const u16* __restrict__ A, const u16* __restrict__ BT,
    float* __restrict__ C) {
  constexpr int Ndim = DMODEL, Kdim = DFF;
  __shared__ u16 As[2][2][256 * 32];
  __shared__ u16 Bs[2][2][256 * 32];

  int midx, nidx;
  bid_map(Ndim / 256, midx, nidx);
  const int m0 = midx << 8;
  const int n0 = nidx << 8;
  const int t = threadIdx.x;
  const int lane = t & 63;
  const int wid = t >> 6;
  const int wr = wid >> 2, wc = wid & 3;
  const int r16 = lane & 15, quad = lane >> 4;

  const int lrow4 = lane >> 2;
  const int sslot = ((lane & 3) ^ ((lane >> 3) & 3)) << 3;
  const u16* Asrc = A + (size_t)(m0 + wid * 16 + lrow4) * Kdim + sslot;
  const u16* Bsrc = BT + (size_t)(n0 + wid * 16 + lrow4) * Kdim + sslot;
  const size_t rstep = (size_t)128 * Kdim;
  const int lb = wid * 512;
  constexpr int ntiles = Kdim >> 6;  // 172

#define SA(tt, kh, bf) do {                                                \
    int ttw = (tt) < ntiles ? (tt) : (tt) - ntiles;                        \
    size_t ko = ((size_t)ttw << 6) + ((kh) << 5);                          \
    GLD16(Asrc + ko,         &As[bf][kh][lb]);                             \
    GLD16(Asrc + ko + rstep, &As[bf][kh][lb + 4096]);                      \
  } while (0)
#define SB(tt, kh, bf) do {                                                \
    int ttw = (tt) < ntiles ? (tt) : (tt) - ntiles;                        \
    size_t ko = ((size_t)ttw << 6) + ((kh) << 5);                          \
    GLD16(Bsrc + ko,         &Bs[bf][kh][lb]);                             \
    GLD16(Bsrc + ko + rstep, &Bs[bf][kh][lb + 4096]);                      \
  } while (0)

  const int fragoff = (quad ^ ((r16 >> 1) & 3)) << 3;
  const int abase = (wr * 128 + r16) * 32 + fragoff;
  const int bbase = (wc * 64 + r16) * 32 + fragoff;

  f32x4 acc[8][4];
  const f32x4 zf = {0.f, 0.f, 0.f, 0.f};
#pragma unroll
  for (int mf = 0; mf < 8; ++mf)
#pragma unroll
    for (int nf = 0; nf < 4; ++nf) acc[mf][nf] = zf;

#define BAR asm volatile("s_barrier" ::: "memory")
#define VM4 asm volatile("s_waitcnt vmcnt(4)" ::: "memory")

#define PH(bf, kk, STG, VMW) do {                                          \
    bf16x8 av[4], bv[4], av2[4];                                           \
    _Pragma("unroll") for (int ii = 0; ii < 4; ++ii)                       \
      av[ii] = *reinterpret_cast<const bf16x8*>(                           \
          &As[bf][kk][abase + ii * 512]);                                  \
    _Pragma("unroll") for (int nn = 0; nn < 4; ++nn)                       \
      bv[nn] = *reinterpret_cast<const bf16x8*>(                           \
          &Bs[bf][kk][bbase + nn * 512]);                                  \
    STG;                                                                   \
    BAR;                                                                   \
    __builtin_amdgcn_s_setprio(1);                                         \
    _Pragma("unroll") for (int ii = 0; ii < 4; ++ii)                       \
      _Pragma("unroll") for (int nn = 0; nn < 4; ++nn)                     \
        acc[ii][nn] = __builtin_amdgcn_mfma_f32_16x16x32_bf16(             \
            av[ii], bv[nn], acc[ii][nn], 0, 0, 0);                         \
    _Pragma("unroll") for (int ii = 0; ii < 4; ++ii)                       \
      av2[ii] = *reinterpret_cast<const bf16x8*>(                          \
          &As[bf][kk][abase + 2048 + ii * 512]);                           \
    _Pragma("unroll") for (int ii = 0; ii < 4; ++ii)                       \
      _Pragma("unroll") for (int nn = 0; nn < 4; ++nn)                     \
        acc[4 + ii][nn] = __builtin_amdgcn_mfma_f32_16x16x32_bf16(         \
            av2[ii], bv[nn], acc[4 + ii][nn], 0, 0, 0);                    \
    __builtin_amdgcn_s_setprio(0);                                         \
    VMW;                                                                   \
    BAR;                                                                   \
  } while (0)

  SA(0, 0, 0); SB(0, 0, 0); SA(0, 1, 0); SB(0, 1, 0); SA(1, 0, 1); SB(1, 0, 1);
  VM4;
  BAR;

  constexpr int NI = ntiles >> 1;  // 86
  for (int it = 0; it < NI; ++it) {
    const int t0 = it * 2;
    PH(0, 0, { SA(t0 + 1, 1, 1); SB(t0 + 1, 1, 1); }, (void)0);
    PH(0, 1, { SA(t0 + 2, 0, 0); SB(t0 + 2, 0, 0); }, VM4);
    PH(1, 0, { SA(t0 + 2, 1, 0); SB(t0 + 2, 1, 0); }, (void)0);
    PH(1, 1, { SA(t0 + 3, 0, 1); SB(t0 + 3, 0, 1); }, VM4);
  }
  asm volatile("s_waitcnt vmcnt(0)" ::: "memory");

  const int rb0 = m0 + wr * 128 + quad * 4;
  const int cb0 = n0 + wc * 64 + r16;
#pragma unroll
  for (int mf = 0; mf < 8; ++mf) {
#pragma unroll
    for (int nf = 0; nf < 4; ++nf) {
      f32x4 v = acc[mf][nf];
      int row = rb0 + mf * 16;
      int col = cb0 + nf * 16;
#pragma unroll
      for (int j = 0; j < 4; ++j)
        C[(size_t)(row + j) * Ndim + col] = v[j];
    }
  }
#undef SA
#undef SB
#undef PH
#undef BAR
#undef VM4
}

extern "C" void kernel_launch(void* const* d_in, const int* in_sizes, int n_in,
                              void* d_out, int out_size, void* d_ws, size_t ws_size,
                              hipStream_t stream) {
  const float* x  = (const float*)d_in[0];
  const int*   qg = (const int*)d_in[1];
  const int*   zg = (const int*)d_in[2];
  const float* sg = (const float*)d_in[3];
  const int*   qu = (const int*)d_in[4];
  const int*   zu = (const int*)d_in[5];
  const float* su = (const float*)d_in[6];
  const int*   qd = (const int*)d_in[7];
  const int*   zd = (const int*)d_in[8];
  const float* sd = (const float*)d_in[9];
  float* out = (float*)d_out;

  char* ws = (char*)d_ws;
  const size_t szXB = (size_t)MROWS * DMODEL * 2;
  const size_t szW  = (size_t)DMODEL * DFF * 2;
  u16* xb  = (u16*)(ws);
  u16* wgT = (u16*)(ws + szXB);
  u16* wuT = (u16*)(ws + szXB + szW);
  u16* wdT = (u16*)(ws + szXB + 2 * szW);
  u16* h   = (u16*)(ws + szXB + 3 * szW);  // [M][DFF] bf16

  k_cvt_x<<<(MROWS * DMODEL) / 1024, 256, 0, stream>>>(x, xb);
  k_dequant_T<<<dim3(DFF / 32, DMODEL / 32), 256, 0, stream>>>(qg, zg, sg, wgT, DMODEL, DFF);
  k_dequant_T<<<dim3(DFF / 32, DMODEL / 32), 256, 0, stream>>>(qu, zu, su, wuT, DMODEL, DFF);
  k_dequant_T<<<dim3(DMODEL / 32, DFF / 32), 256, 0, stream>>>(qd, zd, sd, wdT, DFF, DMODEL);

  // h = silu(x@Wg) * (x@Wu)   — fused, grid = 32 m-blocks * 86 n-blocks
  k_fused<<<(MROWS / 256) * (DFF / 128), 512, 0, stream>>>(xb, wgT, wuT, h);
  // out = h @ Wd
  k_down<<<(MROWS / 256) * (DMODEL / 256), 512, 0, stream>>>(h, wdT, out);
}

// Round 6
// 2287.722 us; speedup vs baseline: 1.1808x; 1.0139x over previous
//
#include <hip/hip_runtime.h>
#include <cstdint>

typedef unsigned short u16;
typedef unsigned int u32;
typedef __bf16 bf16_t;
typedef bf16_t bf16x8 __attribute__((ext_vector_type(8)));
typedef float f32x4 __attribute__((ext_vector_type(4)));

#define DMODEL 4096
#define DFF 11008
#define MROWS 8192

__device__ __forceinline__ u16 f2bf(float f) {
  u32 u = __builtin_bit_cast(u32, f);
  u += 0x7FFFu + ((u >> 16) & 1u);   // RNE
  return (u16)(u >> 16);
}
__device__ __forceinline__ float bf2f(u16 h) {
  return __builtin_bit_cast(float, (u32)h << 16);
}

// async global->LDS, 16B per lane, wave-uniform LDS base + lane*16
#define GLD16(gptr, lptr)                                                  \
  __builtin_amdgcn_global_load_lds(                                        \
      (const __attribute__((address_space(1))) u32*)(gptr),                \
      (__attribute__((address_space(3))) u32*)(lptr), 16, 0, 0)

// ---------------- x -> bf16 ----------------
__global__ void k_cvt_x(const float* __restrict__ x, u16* __restrict__ xb) {
  size_t i = (size_t)blockIdx.x * blockDim.x + threadIdx.x;
  float4 v = reinterpret_cast<const float4*>(x)[i];
  ushort4 o;
  o.x = f2bf(v.x); o.y = f2bf(v.y); o.z = f2bf(v.z); o.w = f2bf(v.w);
  reinterpret_cast<ushort4*>(xb)[i] = o;
}

// ------- dequant (q - z) * s, write TRANSPOSED wT[N][K] as bf16 -------
__global__ void k_dequant_T(const int* __restrict__ q, const int* __restrict__ z,
                            const float* __restrict__ s, u16* __restrict__ wT,
                            int K, int N) {
  __shared__ u16 tile[32][36];
  const int t = threadIdx.x;
  const int n0 = blockIdx.x << 5, k0 = blockIdx.y << 5;
  {
    const int kr = t >> 3, n4 = (t & 7) << 2;
    const int k = k0 + kr, g = k >> 7;
    const int4 qv = *reinterpret_cast<const int4*>(&q[(size_t)k * N + n0 + n4]);
    const int4 zv = *reinterpret_cast<const int4*>(&z[(size_t)g * N + n0 + n4]);
    const float4 sv = *reinterpret_cast<const float4*>(&s[(size_t)g * N + n0 + n4]);
    ushort4 o;
    o.x = f2bf((float)(qv.x - zv.x) * sv.x);
    o.y = f2bf((float)(qv.y - zv.y) * sv.y);
    o.z = f2bf((float)(qv.z - zv.z) * sv.z);
    o.w = f2bf((float)(qv.w - zv.w) * sv.w);
    *reinterpret_cast<ushort4*>(&tile[kr][n4]) = o;
  }
  __syncthreads();
  {
    const int n = t >> 3, ks = (t & 7) << 2;
    ushort4 o;
    o.x = tile[ks + 0][n];
    o.y = tile[ks + 1][n];
    o.z = tile[ks + 2][n];
    o.w = tile[ks + 3][n];
    *reinterpret_cast<ushort4*>(&wT[(size_t)(n0 + n) * K + k0 + ks]) = o;
  }
}

// locality bid map: XCD owns 4 m-rows; 4 consecutive blocks share one B panel.
__device__ __forceinline__ void bid_map(int nbn, int& midx, int& nidx) {
  const int xcd = blockIdx.x & 7, lb = blockIdx.x >> 3;
  midx = xcd * 4 + (lb & 3);
  nidx = lb >> 2;
}

#define BAR asm volatile("s_barrier" ::: "memory")
#define VM4 asm volatile("s_waitcnt vmcnt(4)" ::: "memory")

// ======== fused gate+up: h = silu(x@Wg) * (x@Wu), bf16 out ========
// BM=256, BN=128, BK=64 (2 K-halves), 8 waves (2M x 4N, wave-tile 128x32).
// 4-phase rotation with CROSS-PHASE REGISTER PREFETCH: each phase's 12
// fragment ds_reads are issued during the PREVIOUS phase's MFMA cluster
// (between the two 16-MFMA halves), so the LDS pipe overlaps the MFMA
// pipe. VM4 moved BEFORE BAR1 so every region is vmcnt-confirmed before
// its earliest (prefetch) read — full timeline enumerated safe.
__global__ __launch_bounds__(512, 2) void k_fused(
    const u16* __restrict__ A, const u16* __restrict__ BgT,
    const u16* __restrict__ BuT, u16* __restrict__ H) {
  constexpr int Kdim = DMODEL;
  __shared__ u16 As[2][2][256 * 32];   // 64KB
  __shared__ u16 Bgs[2][2][128 * 32];  // 32KB
  __shared__ u16 Bus[2][2][128 * 32];  // 32KB

  int midx, nidx;
  bid_map(DFF / 128, midx, nidx);
  const int m0 = midx << 8;
  const int n0 = nidx << 7;
  const int t = threadIdx.x;
  const int lane = t & 63;
  const int wid = t >> 6;
  const int wr = wid >> 2, wc = wid & 3;
  const int r16 = lane & 15, quad = lane >> 4;

  const int lrow4 = lane >> 2;
  const int sslot = ((lane & 3) ^ ((lane >> 3) & 3)) << 3;  // u16 units
  const u16* Asrc = A + (size_t)(m0 + wid * 16 + lrow4) * Kdim + sslot;
  const u16* Gsrc = BgT + (size_t)(n0 + wid * 16 + lrow4) * Kdim + sslot;
  const u16* Usrc = BuT + (size_t)(n0 + wid * 16 + lrow4) * Kdim + sslot;
  const size_t rstep = (size_t)128 * Kdim;
  const int lb = wid * 512;
  constexpr int ntiles = Kdim >> 6;  // 64

#define SAF(tt, kh, bf) do {                                               \
    size_t ko = ((size_t)((tt) & (ntiles - 1)) << 6) + ((kh) << 5);        \
    GLD16(Asrc + ko,         &As[bf][kh][lb]);                             \
    GLD16(Asrc + ko + rstep, &As[bf][kh][lb + 4096]);                      \
  } while (0)
#define SGU(tt, kh, bf) do {                                               \
    size_t ko = ((size_t)((tt) & (ntiles - 1)) << 6) + ((kh) << 5);        \
    GLD16(Gsrc + ko, &Bgs[bf][kh][lb]);                                    \
    GLD16(Usrc + ko, &Bus[bf][kh][lb]);                                    \
  } while (0)

  const int fragoff = (quad ^ ((r16 >> 1) & 3)) << 3;
  const int abase = (wr * 128 + r16) * 32 + fragoff;
  const int bbase = (wc * 32 + r16) * 32 + fragoff;

  f32x4 accg[8][2], accu[8][2];
  const f32x4 zf = {0.f, 0.f, 0.f, 0.f};
#pragma unroll
  for (int mf = 0; mf < 8; ++mf)
#pragma unroll
    for (int nf = 0; nf < 2; ++nf) { accg[mf][nf] = zf; accu[mf][nf] = zf; }

  // two static fragment sets (rule #20: no runtime indexing)
  bf16x8 avA[4], av2A[4], bgA[2], buA[2];
  bf16x8 avB[4], av2B[4], bgB[2], buB[2];

#define PFF(av_, av2_, bg_, bu_, bf, kk) do {                              \
    _Pragma("unroll") for (int ii = 0; ii < 4; ++ii) {                     \
      av_[ii] = *reinterpret_cast<const bf16x8*>(                          \
          &As[bf][kk][abase + ii * 512]);                                  \
      av2_[ii] = *reinterpret_cast<const bf16x8*>(                         \
          &As[bf][kk][abase + 2048 + ii * 512]);                           \
    }                                                                      \
    _Pragma("unroll") for (int nn = 0; nn < 2; ++nn) {                     \
      bg_[nn] = *reinterpret_cast<const bf16x8*>(                          \
          &Bgs[bf][kk][bbase + nn * 512]);                                 \
      bu_[nn] = *reinterpret_cast<const bf16x8*>(                          \
          &Bus[bf][kk][bbase + nn * 512]);                                 \
    }                                                                      \
  } while (0)

  // PH: compute with cur set, prefetch next phase's frags mid-cluster.
#define PHF(av_, av2_, bg_, bu_, nav_, nav2_, nbg_, nbu_, STG, VMW, bfn, kkn) \
  do {                                                                     \
    STG;                                                                   \
    VMW;                                                                   \
    BAR;                                                                   \
    __builtin_amdgcn_s_setprio(1);                                         \
    _Pragma("unroll") for (int ii = 0; ii < 4; ++ii)                       \
      _Pragma("unroll") for (int nn = 0; nn < 2; ++nn) {                   \
        accg[ii][nn] = __builtin_amdgcn_mfma_f32_16x16x32_bf16(            \
            av_[ii], bg_[nn], accg[ii][nn], 0, 0, 0);                      \
        accu[ii][nn] = __builtin_amdgcn_mfma_f32_16x16x32_bf16(            \
            av_[ii], bu_[nn], accu[ii][nn], 0, 0, 0);                      \
      }                                                                    \
    PFF(nav_, nav2_, nbg_, nbu_, bfn, kkn);                                \
    _Pragma("unroll") for (int ii = 0; ii < 4; ++ii)                       \
      _Pragma("unroll") for (int nn = 0; nn < 2; ++nn) {                   \
        accg[4 + ii][nn] = __builtin_amdgcn_mfma_f32_16x16x32_bf16(        \
            av2_[ii], bg_[nn], accg[4 + ii][nn], 0, 0, 0);                 \
        accu[4 + ii][nn] = __builtin_amdgcn_mfma_f32_16x16x32_bf16(        \
            av2_[ii], bu_[nn], accu[4 + ii][nn], 0, 0, 0);                 \
      }                                                                    \
    __builtin_amdgcn_s_setprio(0);                                         \
    BAR;                                                                   \
  } while (0)

  // prologue: stage regions for phases 1,2,3; confirm 1,2; prefetch ph1.
  SAF(0, 0, 0); SGU(0, 0, 0); SAF(0, 1, 0); SGU(0, 1, 0);
  SAF(1, 0, 1); SGU(1, 0, 1);
  VM4;
  BAR;
  PFF(avA, av2A, bgA, buA, 0, 0);

  constexpr int NI = ntiles >> 1;  // 32
  for (int it = 0; it < NI; ++it) {
    const int t0 = it * 2;
    PHF(avA, av2A, bgA, buA, avB, av2B, bgB, buB,
        { SAF(t0 + 1, 1, 1); SGU(t0 + 1, 1, 1); }, (void)0, 0, 1);
    PHF(avB, av2B, bgB, buB, avA, av2A, bgA, buA,
        { SAF(t0 + 2, 0, 0); SGU(t0 + 2, 0, 0); }, VM4, 1, 0);
    PHF(avA, av2A, bgA, buA, avB, av2B, bgB, buB,
        { SAF(t0 + 2, 1, 0); SGU(t0 + 2, 1, 0); }, (void)0, 1, 1);
    PHF(avB, av2B, bgB, buB, avA, av2A, bgA, buA,
        { SAF(t0 + 3, 0, 1); SGU(t0 + 3, 0, 1); }, VM4, 0, 0);
  }
  asm volatile("s_waitcnt vmcnt(0)" ::: "memory");

  // epilogue: h = silu(g) * u
  const int rb0 = m0 + wr * 128 + quad * 4;
  const int cb0 = n0 + wc * 32 + r16;
#pragma unroll
  for (int mf = 0; mf < 8; ++mf) {
#pragma unroll
    for (int nf = 0; nf < 2; ++nf) {
      f32x4 vg = accg[mf][nf];
      f32x4 vu = accu[mf][nf];
      int row = rb0 + mf * 16;
      int col = cb0 + nf * 16;
#pragma unroll
      for (int j = 0; j < 4; ++j) {
        float g = vg[j];
        float sv = g / (1.f + __expf(-g));
        H[(size_t)(row + j) * DFF + col] = f2bf(sv * vu[j]);
      }
    }
  }
#undef SAF
#undef SGU
#undef PFF
#undef PHF
}

// ======== down GEMM: out[M, DMODEL] = h @ WdT^T, f32 out ========
// Same cross-phase register-prefetch transform as k_fused.
__global__ __launch_bounds__(512, 2) void k_down(
    const u16* __restrict__ A, const u16* __restrict__ BT,
    float* __restrict__ C) {
  constexpr int Ndim = DMODEL, Kdim = DFF;
  __shared__ u16 As[2][2][256 * 32];
  __shared__ u16 Bs[2][2][256 * 32];

  int midx, nidx;
  bid_map(Ndim / 256, midx, nidx);
  const int m0 = midx << 8;
  const int n0 = nidx << 8;
  const int t = threadIdx.x;
  const int lane = t & 63;
  const int wid = t >> 6;
  const int wr = wid >> 2, wc = wid & 3;
  const int r16 = lane & 15, quad = lane >> 4;

  const int lrow4 = lane >> 2;
  const int sslot = ((lane & 3) ^ ((lane >> 3) & 3)) << 3;
  const u16* Asrc = A + (size_t)(m0 + wid * 16 + lrow4) * Kdim + sslot;
  const u16* Bsrc = BT + (size_t)(n0 + wid * 16 + lrow4) * Kdim + sslot;
  const size_t rstep = (size_t)128 * Kdim;
  const int lb = wid * 512;
  constexpr int ntiles = Kdim >> 6;  // 172

#define SA(tt, kh, bf) do {                                                \
    int ttw = (tt) < ntiles ? (tt) : (tt) - ntiles;                        \
    size_t ko = ((size_t)ttw << 6) + ((kh) << 5);                          \
    GLD16(Asrc + ko,         &As[bf][kh][lb]);                             \
    GLD16(Asrc + ko + rstep, &As[bf][kh][lb + 4096]);                      \
  } while (0)
#define SB(tt, kh, bf) do {                                                \
    int ttw = (tt) < ntiles ? (tt) : (tt) - ntiles;                        \
    size_t ko = ((size_t)ttw << 6) + ((kh) << 5);                          \
    GLD16(Bsrc + ko,         &Bs[bf][kh][lb]);                             \
    GLD16(Bsrc + ko + rstep, &Bs[bf][kh][lb + 4096]);                      \
  } while (0)

  const int fragoff = (quad ^ ((r16 >> 1) & 3)) << 3;
  const int abase = (wr * 128 + r16) * 32 + fragoff;
  const int bbase = (wc * 64 + r16) * 32 + fragoff;

  f32x4 acc[8][4];
  const f32x4 zf = {0.f, 0.f, 0.f, 0.f};
#pragma unroll
  for (int mf = 0; mf < 8; ++mf)
#pragma unroll
    for (int nf = 0; nf < 4; ++nf) acc[mf][nf] = zf;

  bf16x8 avA[4], av2A[4], bvA[4];
  bf16x8 avB[4], av2B[4], bvB[4];

#define PFD(av_, av2_, bv_, bf, kk) do {                                   \
    _Pragma("unroll") for (int ii = 0; ii < 4; ++ii) {                     \
      av_[ii] = *reinterpret_cast<const bf16x8*>(                          \
          &As[bf][kk][abase + ii * 512]);                                  \
      av2_[ii] = *reinterpret_cast<const bf16x8*>(                         \
          &As[bf][kk][abase + 2048 + ii * 512]);                           \
    }                                                                      \
    _Pragma("unroll") for (int nn = 0; nn < 4; ++nn)                       \
      bv_[nn] = *reinterpret_cast<const bf16x8*>(                          \
          &Bs[bf][kk][bbase + nn * 512]);                                  \
  } while (0)

#define PHD(av_, av2_, bv_, nav_, nav2_, nbv_, STG, VMW, bfn, kkn) do {    \
    STG;                                                                   \
    VMW;                                                                   \
    BAR;                                                                   \
    __builtin_amdgcn_s_setprio(1);                                         \
    _Pragma("unroll") for (int ii = 0; ii < 4; ++ii)                       \
      _Pragma("unroll") for (int nn = 0; nn < 4; ++nn)                     \
        acc[ii][nn] = __builtin_amdgcn_mfma_f32_16x16x32_bf16(             \
            av_[ii], bv_[nn], acc[ii][nn], 0, 0, 0);                       \
    PFD(nav_, nav2_, nbv_, bfn, kkn);                                      \
    _Pragma("unroll") for (int ii = 0; ii < 4; ++ii)                       \
      _Pragma("unroll") for (int nn = 0; nn < 4; ++nn)                     \
        acc[4 + ii][nn] = __builtin_amdgcn_mfma_f32_16x16x32_bf16(         \
            av2_[ii], bv_[nn], acc[4 + ii][nn], 0, 0, 0);                  \
    __builtin_amdgcn_s_setprio(0);                                         \
    BAR;                                                                   \
  } while (0)

  SA(0, 0, 0); SB(0, 0, 0); SA(0, 1, 0); SB(0, 1, 0); SA(1, 0, 1); SB(1, 0, 1);
  VM4;
  BAR;
  PFD(avA, av2A, bvA, 0, 0);

  constexpr int NI = ntiles >> 1;  // 86
  for (int it = 0; it < NI; ++it) {
    const int t0 = it * 2;
    PHD(avA, av2A, bvA, avB, av2B, bvB,
        { SA(t0 + 1, 1, 1); SB(t0 + 1, 1, 1); }, (void)0, 0, 1);
    PHD(avB, av2B, bvB, avA, av2A, bvA,
        { SA(t0 + 2, 0, 0); SB(t0 + 2, 0, 0); }, VM4, 1, 0);
    PHD(avA, av2A, bvA, avB, av2B, bvB,
        { SA(t0 + 2, 1, 0); SB(t0 + 2, 1, 0); }, (void)0, 1, 1);
    PHD(avB, av2B, bvB, avA, av2A, bvA,
        { SA(t0 + 3, 0, 1); SB(t0 + 3, 0, 1); }, VM4, 0, 0);
  }
  asm volatile("s_waitcnt vmcnt(0)" ::: "memory");

  const int rb0 = m0 + wr * 128 + quad * 4;
  const int cb0 = n0 + wc * 64 + r16;
#pragma unroll
  for (int mf = 0; mf < 8; ++mf) {
#pragma unroll
    for (int nf = 0; nf < 4; ++nf) {
      f32x4 v = acc[mf][nf];
      int row = rb0 + mf * 16;
      int col = cb0 + nf * 16;
#pragma unroll
      for (int j = 0; j < 4; ++j)
        C[(size_t)(row + j) * Ndim + col] = v[j];
    }
  }
#undef SA
#undef SB
#undef PFD
#undef PHD
}

extern "C" void kernel_launch(void* const* d_in, const int* in_sizes, int n_in,
                              void* d_out, int out_size, void* d_ws, size_t ws_size,
                              hipStream_t stream) {
  const float* x  = (const float*)d_in[0];
  const int*   qg = (const int*)d_in[1];
  const int*   zg = (const int*)d_in[2];
  const float* sg = (const float*)d_in[3];
  const int*   qu = (const int*)d_in[4];
  const int*   zu = (const int*)d_in[5];
  const float* su = (const float*)d_in[6];
  const int*   qd = (const int*)d_in[7];
  const int*   zd = (const int*)d_in[8];
  const float* sd = (const float*)d_in[9];
  float* out = (float*)d_out;

  char* ws = (char*)d_ws;
  const size_t szXB = (size_t)MROWS * DMODEL * 2;
  const size_t szW  = (size_t)DMODEL * DFF * 2;
  u16* xb  = (u16*)(ws);
  u16* wgT = (u16*)(ws + szXB);
  u16* wuT = (u16*)(ws + szXB + szW);
  u16* wdT = (u16*)(ws + szXB + 2 * szW);
  u16* h   = (u16*)(ws + szXB + 3 * szW);  // [M][DFF] bf16

  k_cvt_x<<<(MROWS * DMODEL) / 1024, 256, 0, stream>>>(x, xb);
  k_dequant_T<<<dim3(DFF / 32, DMODEL / 32), 256, 0, stream>>>(qg, zg, sg, wgT, DMODEL, DFF);
  k_dequant_T<<<dim3(DFF / 32, DMODEL / 32), 256, 0, stream>>>(qu, zu, su, wuT, DMODEL, DFF);
  k_dequant_T<<<dim3(DMODEL / 32, DFF / 32), 256, 0, stream>>>(qd, zd, sd, wdT, DFF, DMODEL);

  k_fused<<<(MROWS / 256) * (DFF / 128), 512, 0, stream>>>(xb, wgT, wuT, h);
  k_down<<<(MROWS / 256) * (DMODEL / 256), 512, 0, stream>>>(h, wdT, out);
}